// Round 4
// baseline (99.817 us; speedup 1.0000x reference)
//
#include <hip/hip_runtime.h>
#include <math.h>

#define NWIRES 6
#define DIM 64
#define NTOK 32768            // B*T = 16*2048
#define NBATCH 16
#define TPB 2048              // tokens per batch
#define NMOM 16               // Taylor order: exp(az), |az|<=sqrt(6); rem ~8e-8
#define SQRT6F 2.4494897427831781f

// ---------------------------------------------------------------------------
// Kernel 0: cos/sin of half-angles, 3 circuits x 18 gates.
// cs[circ*36 + g*2 + {0,1}] = {cos,sin}(theta_g/2); g: 0..5 RX, 6..11 RY0, 12..17 RY1
// ---------------------------------------------------------------------------
__global__ void qsa_prep(const float* __restrict__ pq,
                         const float* __restrict__ pk,
                         const float* __restrict__ pv,
                         float* __restrict__ cs) {
    int i = threadIdx.x;
    if (i >= 54) return;
    int circ = i / 18, g = i % 18;
    const float* p = (circ == 0) ? pq : (circ == 1 ? pk : pv);
    float s, c;
    sincosf(0.5f * p[g], &s, &c);
    cs[i * 2 + 0] = c;
    cs[i * 2 + 1] = s;
}

// ---------------------------------------------------------------------------
// Gate helpers: state fully in registers, fully unrolled, compile-time indices.
// Wire j <-> bit (5-j), mask M = 32>>j.
// ---------------------------------------------------------------------------
template<int M>
__device__ __forceinline__ void rx_g(float* re, float* im, float c, float s) {
#pragma unroll
    for (int i = 0; i < DIM; ++i) {
        if (i & M) continue;
        int j = i | M;
        float r0 = re[i], i0 = im[i], r1 = re[j], i1 = im[j];
        re[i] = c * r0 + s * i1;
        im[i] = c * i0 - s * r1;
        re[j] = c * r1 + s * i0;
        im[j] = c * i1 - s * r0;
    }
}

template<int M>
__device__ __forceinline__ void ry_g(float* re, float* im, float c, float s) {
#pragma unroll
    for (int i = 0; i < DIM; ++i) {
        if (i & M) continue;
        int j = i | M;
        float r0 = re[i], i0 = im[i], r1 = re[j], i1 = im[j];
        re[i] = c * r0 - s * r1;
        im[i] = c * i0 - s * i1;
        re[j] = c * r1 + s * r0;
        im[j] = c * i1 + s * i0;
    }
}

template<int MC, int MT>
__device__ __forceinline__ void cnot_g(float* re, float* im) {
#pragma unroll
    for (int i = 0; i < DIM; ++i) {
        if (!(i & MC) || (i & MT)) continue;
        int j = i | MT;
        float tr = re[i]; re[i] = re[j]; re[j] = tr;
        float ti = im[i]; im[i] = im[j]; im[j] = ti;
    }
}

// ---------------------------------------------------------------------------
// Kernel 1: one token/thread, one circuit per blockIdx.y.
// waves_per_eu(2,2): EXACTLY 2 waves/SIMD -> 256-VGPR budget (state needs ~140,
// no spill) PLUS a second resident wave for latency hiding.
// R3 post-mortem: (1,1) was spill-free but VALUBusy=16% -- one wave can't
// cover FMA dep latency. R2: launch_bounds(64,2) is only a MIN -> allocator
// targeted 4 waves at 128 VGPR and spilled 42 MB. Pin both ends.
// ---------------------------------------------------------------------------
__global__ __attribute__((amdgpu_waves_per_eu(2, 2)))
__launch_bounds__(64) void qsa_sim(
        const float* __restrict__ x,
        const float* __restrict__ cs,
        float* __restrict__ zq,
        float* __restrict__ kv) {
    int token = blockIdx.x * 64 + threadIdx.x;
    int circ = blockIdx.y;
    const float* P = cs + circ * 36;

    float re[DIM], im[DIM];
    const float4* xp4 = (const float4*)(x + (size_t)token * DIM);
#pragma unroll
    for (int k = 0; k < DIM / 4; ++k) {
        float4 v = xp4[k];
        re[4*k+0] = v.x; re[4*k+1] = v.y; re[4*k+2] = v.z; re[4*k+3] = v.w;
        im[4*k+0] = 0.f; im[4*k+1] = 0.f; im[4*k+2] = 0.f; im[4*k+3] = 0.f;
    }

    rx_g<32>(re, im, P[0],  P[1]);  ry_g<32>(re, im, P[12], P[13]);
    rx_g<16>(re, im, P[2],  P[3]);  ry_g<16>(re, im, P[14], P[15]);
    rx_g< 8>(re, im, P[4],  P[5]);  ry_g< 8>(re, im, P[16], P[17]);
    rx_g< 4>(re, im, P[6],  P[7]);  ry_g< 4>(re, im, P[18], P[19]);
    rx_g< 2>(re, im, P[8],  P[9]);  ry_g< 2>(re, im, P[20], P[21]);
    rx_g< 1>(re, im, P[10], P[11]); ry_g< 1>(re, im, P[22], P[23]);
    cnot_g<32,16>(re, im);
    cnot_g<16, 8>(re, im);
    cnot_g< 8, 4>(re, im);
    cnot_g< 4, 2>(re, im);
    cnot_g< 2, 1>(re, im);
    cnot_g< 1,32>(re, im);
    ry_g<32>(re, im, P[24], P[25]);
    ry_g<16>(re, im, P[26], P[27]);
    ry_g< 8>(re, im, P[28], P[29]);
    ry_g< 4>(re, im, P[30], P[31]);
    ry_g< 2>(re, im, P[32], P[33]);
    ry_g< 1>(re, im, P[34], P[35]);

    float norm2 = 0.f, s0=0.f, s1=0.f, s2=0.f, s3=0.f, s4=0.f, s5=0.f;
#pragma unroll
    for (int i = 0; i < DIM; ++i) {
        float p = re[i]*re[i] + im[i]*im[i];
        norm2 += p;
        if (!(i & 32)) s0 += p;
        if (!(i & 16)) s1 += p;
        if (!(i &  8)) s2 += p;
        if (!(i &  4)) s3 += p;
        if (!(i &  2)) s4 += p;
        if (!(i &  1)) s5 += p;
    }
    float inv = 1.0f / norm2;
    if (circ == 0) {
        zq[token] = SQRT6F * (2.f*s0 - norm2) * inv;   // a_t, natural-exp scale
    } else if (circ == 1) {
        kv[(size_t)token * 8 + 0] = (2.f*s0 - norm2) * inv;
    } else {
        float* o = kv + (size_t)token * 8;
        o[1] = (2.f*s0 - norm2) * inv;
        o[2] = (2.f*s1 - norm2) * inv;
        o[3] = (2.f*s2 - norm2) * inv;
        o[4] = (2.f*s3 - norm2) * inv;
        o[5] = (2.f*s4 - norm2) * inv;
        o[6] = (2.f*s5 - norm2) * inv;
        o[7] = 0.f;
    }
}

// ---------------------------------------------------------------------------
// Kernel 2: partial power moments per (batch, chunk-of-256).
// S_m = sum z^m, H_{m,w} = sum z^m * v_w, m=0..15.  112 register accumulators,
// butterfly-reduced across the wave; lane 0 stores 112 floats.
// ---------------------------------------------------------------------------
__global__ __attribute__((amdgpu_waves_per_eu(1, 2)))
__launch_bounds__(64) void qsa_moments_partial(
        const float* __restrict__ kv,
        float* __restrict__ mpart) {
    int blk = blockIdx.x;             // 16 batches * 8 chunks
    int b = blk >> 3, c = blk & 7;
    int lane = threadIdx.x;
    float S[NMOM], H[NMOM][6];
#pragma unroll
    for (int m = 0; m < NMOM; ++m) {
        S[m] = 0.f;
#pragma unroll
        for (int w = 0; w < 6; ++w) H[m][w] = 0.f;
    }
    const float* base = kv + ((size_t)(b * TPB + c * 256)) * 8;
#pragma unroll
    for (int r = 0; r < 4; ++r) {
        const float4* e = (const float4*)(base + (size_t)(r * 64 + lane) * 8);
        float4 e0 = e[0], e1 = e[1];
        float z = e0.x;
        float v0 = e0.y, v1 = e0.z, v2 = e0.w, v3 = e1.x, v4 = e1.y, v5 = e1.z;
        float p = 1.f;
#pragma unroll
        for (int m = 0; m < NMOM; ++m) {
            S[m] += p;
            H[m][0] += p * v0; H[m][1] += p * v1; H[m][2] += p * v2;
            H[m][3] += p * v3; H[m][4] += p * v4; H[m][5] += p * v5;
            p *= z;
        }
    }
#pragma unroll
    for (int d = 32; d >= 1; d >>= 1) {
#pragma unroll
        for (int m = 0; m < NMOM; ++m) {
            S[m] += __shfl_xor(S[m], d, 64);
#pragma unroll
            for (int w = 0; w < 6; ++w) H[m][w] += __shfl_xor(H[m][w], d, 64);
        }
    }
    if (lane == 0) {
        float* o = mpart + (size_t)blk * 112;
#pragma unroll
        for (int m = 0; m < NMOM; ++m) {
            float* om = o + m * 7;
            om[0] = S[m];
            om[1] = H[m][0]; om[2] = H[m][1]; om[3] = H[m][2];
            om[4] = H[m][3]; om[5] = H[m][4]; om[6] = H[m][5];
        }
    }
}

// ---------------------------------------------------------------------------
// Kernel 3: combine 8 chunk-partials -> mom[16][112]. 1792 = 256*7 outputs.
// ---------------------------------------------------------------------------
__global__ void qsa_moments_combine(const float* __restrict__ mpart,
                                    float* __restrict__ mom) {
#pragma unroll
    for (int it = 0; it < 7; ++it) {
        int i = it * 256 + threadIdx.x;       // i in [0, 1792)
        int b = i / 112, j = i % 112;
        float s = 0.f;
#pragma unroll
        for (int c = 0; c < 8; ++c) s += mpart[(size_t)(b * 8 + c) * 112 + j];
        mom[(size_t)b * 112 + j] = s;
    }
}

// ---------------------------------------------------------------------------
// Kernel 4: per-token evaluation. den = sum_m p_m S_m, out_w = sum_m p_m H_mw
// with p_m = a^m/m!.  Moment loads are block-uniform -> scalar loads.
// ---------------------------------------------------------------------------
__global__ __launch_bounds__(256) void qsa_eval(
        const float* __restrict__ zq,
        const float* __restrict__ mom,
        float* __restrict__ out) {
    int t = blockIdx.x * 256 + threadIdx.x;
    int b = t >> 11;                          // 2048 tokens per batch
    const float* M = mom + (size_t)b * 112;
    float a = zq[t];
    float den = 0.f, o0 = 0.f, o1 = 0.f, o2 = 0.f, o3 = 0.f, o4 = 0.f, o5 = 0.f;
    float p = 1.f;
#pragma unroll
    for (int m = 0; m < NMOM; ++m) {
        const float* mm = M + m * 7;
        den += p * mm[0];
        o0 += p * mm[1]; o1 += p * mm[2]; o2 += p * mm[3];
        o3 += p * mm[4]; o4 += p * mm[5]; o5 += p * mm[6];
        p *= a * (1.0f / (m + 1));            // p_{m+1} = p_m * a/(m+1)
    }
    float inv = 1.0f / den;
    float* o = out + (size_t)t * 6;
    float2* o2p = (float2*)o;                 // t*24B is 8-aligned
    o2p[0] = make_float2(o0 * inv, o1 * inv);
    o2p[1] = make_float2(o2 * inv, o3 * inv);
    o2p[2] = make_float2(o4 * inv, o5 * inv);
}

// ---------------------------------------------------------------------------
extern "C" void kernel_launch(void* const* d_in, const int* in_sizes, int n_in,
                              void* d_out, int out_size, void* d_ws, size_t ws_size,
                              hipStream_t stream) {
    const float* x  = (const float*)d_in[0];
    const float* pq = (const float*)d_in[1];
    const float* pk = (const float*)d_in[2];
    const float* pv = (const float*)d_in[3];
    float* w = (float*)d_ws;
    // ws (floats): cs[128] | zq[32768] | kv[262144] | mpart[128*112] | mom[16*112]
    float* cs    = w;
    float* zq    = w + 128;
    float* kv    = w + 128 + NTOK;
    float* mpart = w + 128 + NTOK + NTOK * 8;
    float* mom   = mpart + 128 * 112;
    float* out   = (float*)d_out;

    qsa_prep<<<1, 64, 0, stream>>>(pq, pk, pv, cs);
    qsa_sim<<<dim3(NTOK / 64, 3), 64, 0, stream>>>(x, cs, zq, kv);
    qsa_moments_partial<<<NBATCH * 8, 64, 0, stream>>>(kv, mpart);
    qsa_moments_combine<<<1, 256, 0, stream>>>(mpart, mom);
    qsa_eval<<<NTOK / 256, 256, 0, stream>>>(zq, mom, out);
}

// Round 5
// 96.893 us; speedup vs baseline: 1.0302x; 1.0302x over previous
//
#include <hip/hip_runtime.h>
#include <math.h>

#define NWIRES 6
#define DIM 64
#define NTOK 32768            // B*T = 16*2048
#define NBATCH 16
#define TPB 2048              // tokens per batch
#define NMOM 16               // Taylor order: exp(az), |az|<=sqrt(6); rem ~8e-8
#define SQRT6F 2.4494897427831781f

// ---------------------------------------------------------------------------
// Kernel 0: cos/sin of half-angles, 3 circuits x 18 gates.
// cs[circ*36 + g*2 + {0,1}] = {cos,sin}(theta_g/2); g: 0..5 RX, 6..11 RY0, 12..17 RY1
// ---------------------------------------------------------------------------
__global__ void qsa_prep(const float* __restrict__ pq,
                         const float* __restrict__ pk,
                         const float* __restrict__ pv,
                         float* __restrict__ cs) {
    int i = threadIdx.x;
    if (i >= 54) return;
    int circ = i / 18, g = i % 18;
    const float* p = (circ == 0) ? pq : (circ == 1 ? pk : pv);
    float s, c;
    sincosf(0.5f * p[g], &s, &c);
    cs[i * 2 + 0] = c;
    cs[i * 2 + 1] = s;
}

// ---------------------------------------------------------------------------
// Split-state sim: each token uses a LANE PAIR (g even/odd). Lane parity p
// holds the 32 amplitudes with split-bit (wire 0, global mask 32) == p.
// Local index i (5 bits) carries wires 1..5 as masks 16,8,4,2,1.
// Cross-lane via __shfl_xor(.,1) -> DPP quad-perm, VALU-rate.
// ---------------------------------------------------------------------------
__device__ __forceinline__ float pswap(float v) { return __shfl_xor(v, 1, 64); }

template<int M>
__device__ __forceinline__ void rx_l(float* re, float* im, float c, float s) {
#pragma unroll
    for (int i = 0; i < 32; ++i) {
        if (i & M) continue;
        int j = i | M;
        float r0 = re[i], i0 = im[i], r1 = re[j], i1 = im[j];
        re[i] = c * r0 + s * i1;
        im[i] = c * i0 - s * r1;
        re[j] = c * r1 + s * i0;
        im[j] = c * i1 - s * r0;
    }
}

template<int M>
__device__ __forceinline__ void ry_l(float* re, float* im, float c, float s) {
#pragma unroll
    for (int i = 0; i < 32; ++i) {
        if (i & M) continue;
        int j = i | M;
        float r0 = re[i], i0 = im[i], r1 = re[j], i1 = im[j];
        re[i] = c * r0 - s * r1;
        im[i] = c * i0 - s * i1;
        re[j] = c * r1 + s * r0;
        im[j] = c * i1 + s * i0;
    }
}

template<int MC, int MT>
__device__ __forceinline__ void cnot_l(float* re, float* im) {
#pragma unroll
    for (int i = 0; i < 32; ++i) {
        if (!(i & MC) || (i & MT)) continue;
        int j = i | MT;
        float tr = re[i]; re[i] = re[j]; re[j] = tr;
        float ti = im[i]; im[i] = im[j]; im[j] = ti;
    }
}

// RX on split wire: a_even' = c*a_e - i s*a_o ; a_odd' = -i s*a_e + c*a_o.
// Both parities reduce to: re' = c*re + s*im_partner, im' = c*im - s*re_partner.
__device__ __forceinline__ void rx_s(float* re, float* im, float c, float s) {
#pragma unroll
    for (int i = 0; i < 32; ++i) {
        float pre = pswap(re[i]), pim = pswap(im[i]);
        re[i] = c * re[i] + s * pim;
        im[i] = c * im[i] - s * pre;
    }
}

// RY on split wire: new = c*mine + ss*partner, ss = (p ? +s : -s).
__device__ __forceinline__ void ry_s(float* re, float* im, float c, float ss) {
#pragma unroll
    for (int i = 0; i < 32; ++i) {
        float pre = pswap(re[i]), pim = pswap(im[i]);
        re[i] = c * re[i] + ss * pre;
        im[i] = c * im[i] + ss * pim;
    }
}

// CNOT(control=wire0(split), target=wire1(mask16)): odd-parity lane swaps pairs.
__device__ __forceinline__ void cnot_c01(float* re, float* im, int p) {
#pragma unroll
    for (int i = 0; i < 32; ++i) {
        if (i & 16) continue;
        int j = i | 16;
        float r0 = re[i], r1 = re[j], i0 = im[i], i1 = im[j];
        re[i] = p ? r1 : r0;  re[j] = p ? r0 : r1;
        im[i] = p ? i1 : i0;  im[j] = p ? i0 : i1;
    }
}

// CNOT(control=wire5(local mask 1), target=wire0(split)): odd local indices
// exchange with partner lane (symmetric swap -> plain shuffle replace).
__device__ __forceinline__ void cnot_c50(float* re, float* im) {
#pragma unroll
    for (int i = 1; i < 32; i += 2) {
        re[i] = pswap(re[i]);
        im[i] = pswap(im[i]);
    }
}

// ---------------------------------------------------------------------------
// Kernel 1: 2 threads per token; blockIdx.y = circuit. ~64 floats state/lane
// -> fits at 4-5 waves/SIMD (R4 post-mortem: 128-float/thread state has no
// spill-free multi-wave operating point; splitting the state is the fix).
// waves_per_eu(4,8): VGPR cap 128, occupancy floats 4..8.
// ---------------------------------------------------------------------------
__global__ __attribute__((amdgpu_waves_per_eu(4, 8)))
__launch_bounds__(64) void qsa_sim(
        const float* __restrict__ x,
        const float* __restrict__ cs,
        float* __restrict__ zq,
        float* __restrict__ kv) {
    int g = blockIdx.x * 64 + threadIdx.x;
    int p = g & 1;                 // which half of the state this lane holds
    int token = g >> 1;
    int circ = blockIdx.y;
    const float* P = cs + circ * 36;

    float re[32], im[32];
    const float4* xp4 = (const float4*)(x + (size_t)g * 32);  // contiguous!
#pragma unroll
    for (int k = 0; k < 8; ++k) {
        float4 v = xp4[k];
        re[4*k+0] = v.x; re[4*k+1] = v.y; re[4*k+2] = v.z; re[4*k+3] = v.w;
        im[4*k+0] = 0.f; im[4*k+1] = 0.f; im[4*k+2] = 0.f; im[4*k+3] = 0.f;
    }
    float sgn = p ? 1.f : -1.f;

    // RX layer then RY0 layer (gates on distinct wires commute)
    rx_s(re, im, P[0], P[1]);
    rx_l<16>(re, im, P[2],  P[3]);
    rx_l< 8>(re, im, P[4],  P[5]);
    rx_l< 4>(re, im, P[6],  P[7]);
    rx_l< 2>(re, im, P[8],  P[9]);
    rx_l< 1>(re, im, P[10], P[11]);
    ry_s(re, im, P[12], sgn * P[13]);
    ry_l<16>(re, im, P[14], P[15]);
    ry_l< 8>(re, im, P[16], P[17]);
    ry_l< 4>(re, im, P[18], P[19]);
    ry_l< 2>(re, im, P[20], P[21]);
    ry_l< 1>(re, im, P[22], P[23]);
    // CNOT ring (0,1)(1,2)(2,3)(3,4)(4,5)(5,0)
    cnot_c01(re, im, p);
    cnot_l<16, 8>(re, im);
    cnot_l< 8, 4>(re, im);
    cnot_l< 4, 2>(re, im);
    cnot_l< 2, 1>(re, im);
    cnot_c50(re, im);
    // final RY layer
    ry_s(re, im, P[24], sgn * P[25]);
    ry_l<16>(re, im, P[26], P[27]);
    ry_l< 8>(re, im, P[28], P[29]);
    ry_l< 4>(re, im, P[30], P[31]);
    ry_l< 2>(re, im, P[32], P[33]);
    ry_l< 1>(re, im, P[34], P[35]);

    // probabilities: local partial sums, then one cross-lane combine
    float nl = 0.f, t1=0.f, t2=0.f, t3=0.f, t4=0.f, t5=0.f;
#pragma unroll
    for (int i = 0; i < 32; ++i) {
        float pi = re[i]*re[i] + im[i]*im[i];
        nl += pi;
        if (!(i & 16)) t1 += pi;
        if (!(i &  8)) t2 += pi;
        if (!(i &  4)) t3 += pi;
        if (!(i &  2)) t4 += pi;
        if (!(i &  1)) t5 += pi;
    }
    float np = pswap(nl);
    float norm2 = nl + np;
    float S0 = p ? np : nl;        // even-parity half = global bit5==0
    float inv = 1.0f / norm2;
    float z0 = (2.f * S0 - norm2) * inv;

    if (circ == 0) {
        if (p == 0) zq[token] = SQRT6F * z0;          // a_t, natural-exp scale
    } else if (circ == 1) {
        if (p == 0) kv[(size_t)token * 8] = z0;
    } else {
        float S1 = t1 + pswap(t1);
        float S2 = t2 + pswap(t2);
        float S3 = t3 + pswap(t3);
        float S4 = t4 + pswap(t4);
        float S5 = t5 + pswap(t5);
        float z1 = (2.f*S1 - norm2) * inv;
        float z2 = (2.f*S2 - norm2) * inv;
        float z3 = (2.f*S3 - norm2) * inv;
        float z4 = (2.f*S4 - norm2) * inv;
        float z5 = (2.f*S5 - norm2) * inv;
        float* o = kv + (size_t)token * 8;
        if (p == 0) { o[1] = z0; o[2] = z1; o[3] = z2; }
        else        { o[4] = z3; o[5] = z4; o[6] = z5; }
    }
}

// ---------------------------------------------------------------------------
// Kernel 2: partial power moments per (batch, chunk-of-256).
// S_m = sum z^m, H_{m,w} = sum z^m * v_w, m=0..15.  112 register accumulators,
// butterfly-reduced across the wave; lane 0 stores 112 floats.
// ---------------------------------------------------------------------------
__global__ __attribute__((amdgpu_waves_per_eu(1, 2)))
__launch_bounds__(64) void qsa_moments_partial(
        const float* __restrict__ kv,
        float* __restrict__ mpart) {
    int blk = blockIdx.x;             // 16 batches * 8 chunks
    int b = blk >> 3, c = blk & 7;
    int lane = threadIdx.x;
    float S[NMOM], H[NMOM][6];
#pragma unroll
    for (int m = 0; m < NMOM; ++m) {
        S[m] = 0.f;
#pragma unroll
        for (int w = 0; w < 6; ++w) H[m][w] = 0.f;
    }
    const float* base = kv + ((size_t)(b * TPB + c * 256)) * 8;
#pragma unroll
    for (int r = 0; r < 4; ++r) {
        const float4* e = (const float4*)(base + (size_t)(r * 64 + lane) * 8);
        float4 e0 = e[0], e1 = e[1];
        float z = e0.x;
        float v0 = e0.y, v1 = e0.z, v2 = e0.w, v3 = e1.x, v4 = e1.y, v5 = e1.z;
        float pw = 1.f;
#pragma unroll
        for (int m = 0; m < NMOM; ++m) {
            S[m] += pw;
            H[m][0] += pw * v0; H[m][1] += pw * v1; H[m][2] += pw * v2;
            H[m][3] += pw * v3; H[m][4] += pw * v4; H[m][5] += pw * v5;
            pw *= z;
        }
    }
#pragma unroll
    for (int d = 32; d >= 1; d >>= 1) {
#pragma unroll
        for (int m = 0; m < NMOM; ++m) {
            S[m] += __shfl_xor(S[m], d, 64);
#pragma unroll
            for (int w = 0; w < 6; ++w) H[m][w] += __shfl_xor(H[m][w], d, 64);
        }
    }
    if (lane == 0) {
        float* o = mpart + (size_t)blk * 112;
#pragma unroll
        for (int m = 0; m < NMOM; ++m) {
            float* om = o + m * 7;
            om[0] = S[m];
            om[1] = H[m][0]; om[2] = H[m][1]; om[3] = H[m][2];
            om[4] = H[m][3]; om[5] = H[m][4]; om[6] = H[m][5];
        }
    }
}

// ---------------------------------------------------------------------------
// Kernel 3: combine 8 chunk-partials -> mom[16][112]. 1792 = 256*7 outputs.
// ---------------------------------------------------------------------------
__global__ void qsa_moments_combine(const float* __restrict__ mpart,
                                    float* __restrict__ mom) {
#pragma unroll
    for (int it = 0; it < 7; ++it) {
        int i = it * 256 + threadIdx.x;       // i in [0, 1792)
        int b = i / 112, j = i % 112;
        float s = 0.f;
#pragma unroll
        for (int c = 0; c < 8; ++c) s += mpart[(size_t)(b * 8 + c) * 112 + j];
        mom[(size_t)b * 112 + j] = s;
    }
}

// ---------------------------------------------------------------------------
// Kernel 4: per-token evaluation. den = sum_m p_m S_m, out_w = sum_m p_m H_mw
// with p_m = a^m/m!.  Moment loads are block-uniform -> scalar loads.
// ---------------------------------------------------------------------------
__global__ __launch_bounds__(256) void qsa_eval(
        const float* __restrict__ zq,
        const float* __restrict__ mom,
        float* __restrict__ out) {
    int t = blockIdx.x * 256 + threadIdx.x;
    int b = t >> 11;                          // 2048 tokens per batch
    const float* M = mom + (size_t)b * 112;
    float a = zq[t];
    float den = 0.f, o0 = 0.f, o1 = 0.f, o2 = 0.f, o3 = 0.f, o4 = 0.f, o5 = 0.f;
    float pw = 1.f;
#pragma unroll
    for (int m = 0; m < NMOM; ++m) {
        const float* mm = M + m * 7;
        den += pw * mm[0];
        o0 += pw * mm[1]; o1 += pw * mm[2]; o2 += pw * mm[3];
        o3 += pw * mm[4]; o4 += pw * mm[5]; o5 += pw * mm[6];
        pw *= a * (1.0f / (m + 1));           // p_{m+1} = p_m * a/(m+1)
    }
    float inv = 1.0f / den;
    float* o = out + (size_t)t * 6;
    float2* o2p = (float2*)o;                 // t*24B is 8-aligned
    o2p[0] = make_float2(o0 * inv, o1 * inv);
    o2p[1] = make_float2(o2 * inv, o3 * inv);
    o2p[2] = make_float2(o4 * inv, o5 * inv);
}

// ---------------------------------------------------------------------------
extern "C" void kernel_launch(void* const* d_in, const int* in_sizes, int n_in,
                              void* d_out, int out_size, void* d_ws, size_t ws_size,
                              hipStream_t stream) {
    const float* x  = (const float*)d_in[0];
    const float* pq = (const float*)d_in[1];
    const float* pk = (const float*)d_in[2];
    const float* pv = (const float*)d_in[3];
    float* w = (float*)d_ws;
    // ws (floats): cs[128] | zq[32768] | kv[262144] | mpart[128*112] | mom[16*112]
    float* cs    = w;
    float* zq    = w + 128;
    float* kv    = w + 128 + NTOK;
    float* mpart = w + 128 + NTOK + NTOK * 8;
    float* mom   = mpart + 128 * 112;
    float* out   = (float*)d_out;

    qsa_prep<<<1, 64, 0, stream>>>(pq, pk, pv, cs);
    qsa_sim<<<dim3(NTOK * 2 / 64, 3), 64, 0, stream>>>(x, cs, zq, kv);
    qsa_moments_partial<<<NBATCH * 8, 64, 0, stream>>>(kv, mpart);
    qsa_moments_combine<<<1, 256, 0, stream>>>(mpart, mom);
    qsa_eval<<<NTOK / 256, 256, 0, stream>>>(zq, mom, out);
}

// Round 6
// 95.143 us; speedup vs baseline: 1.0491x; 1.0184x over previous
//
#include <hip/hip_runtime.h>
#include <math.h>

#define NWIRES 6
#define DIM 64
#define NTOK 32768            // B*T = 16*2048
#define NBATCH 16
#define TPB 2048              // tokens per batch
#define NMOM 16               // Taylor order: exp(az), |az|<=sqrt(6); rem ~8e-8
#define SQRT6F 2.4494897427831781f

// ---------------------------------------------------------------------------
// Kernel 0: cos/sin of half-angles, 3 circuits x 18 gates.
// cs[circ*36 + g*2 + {0,1}] = {cos,sin}(theta_g/2); g: 0..5 RX, 6..11 RY0, 12..17 RY1
// ---------------------------------------------------------------------------
__global__ void qsa_prep(const float* __restrict__ pq,
                         const float* __restrict__ pk,
                         const float* __restrict__ pv,
                         float* __restrict__ cs) {
    int i = threadIdx.x;
    if (i >= 54) return;
    int circ = i / 18, g = i % 18;
    const float* p = (circ == 0) ? pq : (circ == 1 ? pk : pv);
    float s, c;
    sincosf(0.5f * p[g], &s, &c);
    cs[i * 2 + 0] = c;
    cs[i * 2 + 1] = s;
}

// ---------------------------------------------------------------------------
// 4-way split-state sim: 4 lanes per token. Lane quad-id l = (p0,p1) holds the
// 16 amplitudes with wire0==p0 (global mask 32), wire1==p1 (mask 16).
// Local 4-bit index i = wires 2..5 as masks 8,4,2,1.
// Cross-lane at distance 1/2 -> DPP quad_perm, VALU rate, no DS pipe.
// R5 post-mortem: allocator always targets its occupancy heuristic and spills
// whatever doesn't fit; so make live state (~32 floats + temps) fit 64 VGPRs.
// ---------------------------------------------------------------------------
template<int D>
__device__ __forceinline__ float psw(float v) { return __shfl_xor(v, D, 64); }

template<int M>
__device__ __forceinline__ void rx_l(float* re, float* im, float c, float s) {
#pragma unroll
    for (int i = 0; i < 16; ++i) {
        if (i & M) continue;
        int j = i | M;
        float r0 = re[i], i0 = im[i], r1 = re[j], i1 = im[j];
        re[i] = c * r0 + s * i1;
        im[i] = c * i0 - s * r1;
        re[j] = c * r1 + s * i0;
        im[j] = c * i1 - s * r0;
    }
}

template<int M>
__device__ __forceinline__ void ry_l(float* re, float* im, float c, float s) {
#pragma unroll
    for (int i = 0; i < 16; ++i) {
        if (i & M) continue;
        int j = i | M;
        float r0 = re[i], i0 = im[i], r1 = re[j], i1 = im[j];
        re[i] = c * r0 - s * r1;
        im[i] = c * i0 - s * i1;
        re[j] = c * r1 + s * r0;
        im[j] = c * i1 + s * i0;
    }
}

template<int MC, int MT>
__device__ __forceinline__ void cnot_l(float* re, float* im) {
#pragma unroll
    for (int i = 0; i < 16; ++i) {
        if (!(i & MC) || (i & MT)) continue;
        int j = i | MT;
        float tr = re[i]; re[i] = re[j]; re[j] = tr;
        float ti = im[i]; im[i] = im[j]; im[j] = ti;
    }
}

// RX on a lane-split wire (distance D): both parities reduce to
// re' = c*re + s*im_partner ; im' = c*im - s*re_partner.
template<int D>
__device__ __forceinline__ void rx_s(float* re, float* im, float c, float s) {
#pragma unroll
    for (int i = 0; i < 16; ++i) {
        float pre = psw<D>(re[i]), pim = psw<D>(im[i]);
        re[i] = c * re[i] + s * pim;
        im[i] = c * im[i] - s * pre;
    }
}

// RY on a lane-split wire: new = c*mine + ss*partner, ss = (parity ? +s : -s).
template<int D>
__device__ __forceinline__ void ry_s(float* re, float* im, float c, float ss) {
#pragma unroll
    for (int i = 0; i < 16; ++i) {
        float pre = psw<D>(re[i]), pim = psw<D>(im[i]);
        re[i] = c * re[i] + ss * pre;
        im[i] = c * im[i] + ss * pim;
    }
}

__global__ __launch_bounds__(256) void qsa_sim(
        const float* __restrict__ x,
        const float* __restrict__ cs,
        float* __restrict__ zq,
        float* __restrict__ kv) {
    int g = blockIdx.x * 256 + threadIdx.x;   // 4 lanes per token
    int l = g & 3;
    int p0 = (l >> 1) & 1, p1 = l & 1;
    int token = g >> 2;
    int circ = blockIdx.y;
    const float* P = cs + circ * 36;

    float re[16], im[16];
    const float4* xp4 = (const float4*)(x + (size_t)g * 16);  // contiguous
#pragma unroll
    for (int k = 0; k < 4; ++k) {
        float4 v = xp4[k];
        re[4*k+0] = v.x; re[4*k+1] = v.y; re[4*k+2] = v.z; re[4*k+3] = v.w;
        im[4*k+0] = 0.f; im[4*k+1] = 0.f; im[4*k+2] = 0.f; im[4*k+3] = 0.f;
    }

    // RX layer (wires 0..5), then RY0 layer (distinct wires commute)
    rx_s<2>(re, im, P[0], P[1]);              // wire0 (lane bit1)
    rx_s<1>(re, im, P[2], P[3]);              // wire1 (lane bit0)
    rx_l<8>(re, im, P[4],  P[5]);
    rx_l<4>(re, im, P[6],  P[7]);
    rx_l<2>(re, im, P[8],  P[9]);
    rx_l<1>(re, im, P[10], P[11]);
    ry_s<2>(re, im, P[12], p0 ? P[13] : -P[13]);
    ry_s<1>(re, im, P[14], p1 ? P[15] : -P[15]);
    ry_l<8>(re, im, P[16], P[17]);
    ry_l<4>(re, im, P[18], P[19]);
    ry_l<2>(re, im, P[20], P[21]);
    ry_l<1>(re, im, P[22], P[23]);

    // CNOT ring (0,1)(1,2)(2,3)(3,4)(4,5)(5,0), applied in order.
    // (0,1): lanes with p0==1 exchange whole halves with lane^1.
#pragma unroll
    for (int i = 0; i < 16; ++i) {
        float tr = psw<1>(re[i]), ti = psw<1>(im[i]);
        re[i] = p0 ? tr : re[i];
        im[i] = p0 ? ti : im[i];
    }
    // (1,2): lanes with p1==1 swap local i <-> i|8.
#pragma unroll
    for (int i = 0; i < 8; ++i) {
        int j = i | 8;
        float ra = re[i], rb = re[j], ia = im[i], ib = im[j];
        re[i] = p1 ? rb : ra;  re[j] = p1 ? ra : rb;
        im[i] = p1 ? ib : ia;  im[j] = p1 ? ia : ib;
    }
    cnot_l<8, 4>(re, im);
    cnot_l<4, 2>(re, im);
    cnot_l<2, 1>(re, im);
    // (5,0): odd local indices exchange symmetrically with lane^2.
#pragma unroll
    for (int i = 1; i < 16; i += 2) {
        re[i] = psw<2>(re[i]);
        im[i] = psw<2>(im[i]);
    }

    // final RY layer
    ry_s<2>(re, im, P[24], p0 ? P[25] : -P[25]);
    ry_s<1>(re, im, P[26], p1 ? P[27] : -P[27]);
    ry_l<8>(re, im, P[28], P[29]);
    ry_l<4>(re, im, P[30], P[31]);
    ry_l<2>(re, im, P[32], P[33]);
    ry_l<1>(re, im, P[34], P[35]);

    // local |amp|^2 partials, then quad reductions (all quad-uniform results)
    float nl = 0.f, u2 = 0.f, u3 = 0.f, u4 = 0.f, u5 = 0.f;
#pragma unroll
    for (int i = 0; i < 16; ++i) {
        float pi = re[i]*re[i] + im[i]*im[i];
        nl += pi;
        if (!(i & 8)) u2 += pi;
        if (!(i & 4)) u3 += pi;
        if (!(i & 2)) u4 += pi;
        if (!(i & 1)) u5 += pi;
    }
    auto qsum = [](float v) { v += psw<1>(v); v += psw<2>(v); return v; };
    float norm2 = qsum(nl);
    float S0 = qsum(p0 ? 0.f : nl);
    float inv = 1.0f / norm2;
    float z0 = (2.f * S0 - norm2) * inv;

    if (circ == 0) {
        if (l == 0) zq[token] = SQRT6F * z0;          // a_t, natural-exp scale
    } else if (circ == 1) {
        if (l == 0) kv[(size_t)token * 8] = z0;
    } else {
        float S1 = qsum(p1 ? 0.f : nl);
        float S2 = qsum(u2), S3 = qsum(u3), S4 = qsum(u4), S5 = qsum(u5);
        float z1 = (2.f*S1 - norm2) * inv;
        float z2 = (2.f*S2 - norm2) * inv;
        float z3 = (2.f*S3 - norm2) * inv;
        float z4 = (2.f*S4 - norm2) * inv;
        float z5 = (2.f*S5 - norm2) * inv;
        float* o = kv + (size_t)token * 8;
        if (l == 0)      { o[1] = z0; o[2] = z1; o[3] = z2; }
        else if (l == 1) { o[4] = z3; o[5] = z4; o[6] = z5; }
    }
}

// ---------------------------------------------------------------------------
// Kernel 2: partial power moments per (batch, chunk-of-256).
// S_m = sum z^m, H_{m,w} = sum z^m * v_w, m=0..15.  112 register accumulators,
// butterfly-reduced across the wave; lane 0 stores 112 floats.
// ---------------------------------------------------------------------------
__global__ __attribute__((amdgpu_waves_per_eu(1, 2)))
__launch_bounds__(64) void qsa_moments_partial(
        const float* __restrict__ kv,
        float* __restrict__ mpart) {
    int blk = blockIdx.x;             // 16 batches * 8 chunks
    int b = blk >> 3, c = blk & 7;
    int lane = threadIdx.x;
    float S[NMOM], H[NMOM][6];
#pragma unroll
    for (int m = 0; m < NMOM; ++m) {
        S[m] = 0.f;
#pragma unroll
        for (int w = 0; w < 6; ++w) H[m][w] = 0.f;
    }
    const float* base = kv + ((size_t)(b * TPB + c * 256)) * 8;
#pragma unroll
    for (int r = 0; r < 4; ++r) {
        const float4* e = (const float4*)(base + (size_t)(r * 64 + lane) * 8);
        float4 e0 = e[0], e1 = e[1];
        float z = e0.x;
        float v0 = e0.y, v1 = e0.z, v2 = e0.w, v3 = e1.x, v4 = e1.y, v5 = e1.z;
        float pw = 1.f;
#pragma unroll
        for (int m = 0; m < NMOM; ++m) {
            S[m] += pw;
            H[m][0] += pw * v0; H[m][1] += pw * v1; H[m][2] += pw * v2;
            H[m][3] += pw * v3; H[m][4] += pw * v4; H[m][5] += pw * v5;
            pw *= z;
        }
    }
#pragma unroll
    for (int d = 32; d >= 1; d >>= 1) {
#pragma unroll
        for (int m = 0; m < NMOM; ++m) {
            S[m] += __shfl_xor(S[m], d, 64);
#pragma unroll
            for (int w = 0; w < 6; ++w) H[m][w] += __shfl_xor(H[m][w], d, 64);
        }
    }
    if (lane == 0) {
        float* o = mpart + (size_t)blk * 112;
#pragma unroll
        for (int m = 0; m < NMOM; ++m) {
            float* om = o + m * 7;
            om[0] = S[m];
            om[1] = H[m][0]; om[2] = H[m][1]; om[3] = H[m][2];
            om[4] = H[m][3]; om[5] = H[m][4]; om[6] = H[m][5];
        }
    }
}

// ---------------------------------------------------------------------------
// Kernel 3: combine 8 chunk-partials -> mom[16][112]. 1792 = 256*7 outputs.
// ---------------------------------------------------------------------------
__global__ void qsa_moments_combine(const float* __restrict__ mpart,
                                    float* __restrict__ mom) {
#pragma unroll
    for (int it = 0; it < 7; ++it) {
        int i = it * 256 + threadIdx.x;       // i in [0, 1792)
        int b = i / 112, j = i % 112;
        float s = 0.f;
#pragma unroll
        for (int c = 0; c < 8; ++c) s += mpart[(size_t)(b * 8 + c) * 112 + j];
        mom[(size_t)b * 112 + j] = s;
    }
}

// ---------------------------------------------------------------------------
// Kernel 4: per-token evaluation. den = sum_m p_m S_m, out_w = sum_m p_m H_mw
// with p_m = a^m/m!.  Moment loads are block-uniform -> scalar loads.
// ---------------------------------------------------------------------------
__global__ __launch_bounds__(256) void qsa_eval(
        const float* __restrict__ zq,
        const float* __restrict__ mom,
        float* __restrict__ out) {
    int t = blockIdx.x * 256 + threadIdx.x;
    int b = t >> 11;                          // 2048 tokens per batch
    const float* M = mom + (size_t)b * 112;
    float a = zq[t];
    float den = 0.f, o0 = 0.f, o1 = 0.f, o2 = 0.f, o3 = 0.f, o4 = 0.f, o5 = 0.f;
    float pw = 1.f;
#pragma unroll
    for (int m = 0; m < NMOM; ++m) {
        const float* mm = M + m * 7;
        den += pw * mm[0];
        o0 += pw * mm[1]; o1 += pw * mm[2]; o2 += pw * mm[3];
        o3 += pw * mm[4]; o4 += pw * mm[5]; o5 += pw * mm[6];
        pw *= a * (1.0f / (m + 1));           // p_{m+1} = p_m * a/(m+1)
    }
    float inv = 1.0f / den;
    float* o = out + (size_t)t * 6;
    float2* o2p = (float2*)o;                 // t*24B is 8-aligned
    o2p[0] = make_float2(o0 * inv, o1 * inv);
    o2p[1] = make_float2(o2 * inv, o3 * inv);
    o2p[2] = make_float2(o4 * inv, o5 * inv);
}

// ---------------------------------------------------------------------------
extern "C" void kernel_launch(void* const* d_in, const int* in_sizes, int n_in,
                              void* d_out, int out_size, void* d_ws, size_t ws_size,
                              hipStream_t stream) {
    const float* x  = (const float*)d_in[0];
    const float* pq = (const float*)d_in[1];
    const float* pk = (const float*)d_in[2];
    const float* pv = (const float*)d_in[3];
    float* w = (float*)d_ws;
    // ws (floats): cs[128] | zq[32768] | kv[262144] | mpart[128*112] | mom[16*112]
    float* cs    = w;
    float* zq    = w + 128;
    float* kv    = w + 128 + NTOK;
    float* mpart = w + 128 + NTOK + NTOK * 8;
    float* mom   = mpart + 128 * 112;
    float* out   = (float*)d_out;

    qsa_prep<<<1, 64, 0, stream>>>(pq, pk, pv, cs);
    qsa_sim<<<dim3(NTOK * 4 / 256, 3), 256, 0, stream>>>(x, cs, zq, kv);
    qsa_moments_partial<<<NBATCH * 8, 64, 0, stream>>>(kv, mpart);
    qsa_moments_combine<<<1, 256, 0, stream>>>(mpart, mom);
    qsa_eval<<<NTOK / 256, 256, 0, stream>>>(zq, mom, out);
}

// Round 7
// 90.718 us; speedup vs baseline: 1.1003x; 1.0488x over previous
//
#include <hip/hip_runtime.h>
#include <math.h>

#define NWIRES 6
#define DIM 64
#define NTOK 32768            // B*T = 16*2048
#define NBATCH 16
#define TPB 2048              // tokens per batch
#define NMOM 16               // Taylor order: exp(az), |az|<=sqrt(6); rem ~8e-8
#define SQRT6F 2.4494897427831781f
#define CSTRIDE 160           // per-circuit table stride (floats)

// ---------------------------------------------------------------------------
// Kernel 0: per-circuit tables.
// T[0..63]   = cos(d_b), T[64..127] = sin(d_b), d_b = sum_j (th_rx[j]/2)*(-1)^{b_j}
//   (RX layer = W diag(e^{-i d}) W; on real input: re0 = W cosd W psi,
//    im0 = W sind W psi up to sign/scale, both irrelevant to <Z>).
// T[128 + (layer*6+j)*2 + {0,1}] = {cos,sin}(th_ry/2), layer 0 = RY0, 1 = RY1.
// ---------------------------------------------------------------------------
__global__ void qsa_prep(const float* __restrict__ pq,
                         const float* __restrict__ pk,
                         const float* __restrict__ pv,
                         float* __restrict__ cs) {
    int b = threadIdx.x;      // 64 threads
    for (int circ = 0; circ < 3; ++circ) {
        const float* p = (circ == 0) ? pq : (circ == 1 ? pk : pv);
        float* T = cs + circ * CSTRIDE;
        float d = 0.f;
#pragma unroll
        for (int j = 0; j < 6; ++j)
            d += 0.5f * p[j] * ((b & (32 >> j)) ? -1.f : 1.f);
        float sd, cd;
        sincosf(d, &sd, &cd);
        T[b] = cd;
        T[64 + b] = sd;
        if (b < 12) {                       // p[6..11]=RY0, p[12..17]=RY1
            float s, c;
            sincosf(0.5f * p[6 + b], &s, &c);
            T[128 + b * 2 + 0] = c;
            T[128 + b * 2 + 1] = s;
        }
    }
}

// ---------------------------------------------------------------------------
// Real-state helpers: fully unrolled, compile-time indices, NO cross-lane.
// Wire j <-> bit (5-j), mask M = 32>>j.
// ---------------------------------------------------------------------------
template<int M>
__device__ __forceinline__ void whad(float* v) {       // Walsh butterfly stage
#pragma unroll
    for (int i = 0; i < DIM; ++i) {
        if (i & M) continue;
        int j = i | M;
        float a = v[i], b = v[j];
        v[i] = a + b;
        v[j] = a - b;
    }
}

template<int M>
__device__ __forceinline__ void ryr(float* v, float c, float s) {  // real RY
#pragma unroll
    for (int i = 0; i < DIM; ++i) {
        if (i & M) continue;
        int j = i | M;
        float a = v[i], b = v[j];
        v[i] = c * a - s * b;
        v[j] = s * a + c * b;
    }
}

template<int MC, int MT>
__device__ __forceinline__ void cnr(float* v) {        // real CNOT (rename)
#pragma unroll
    for (int i = 0; i < DIM; ++i) {
        if (!(i & MC) || (i & MT)) continue;
        int j = i | MT;
        float t = v[i]; v[i] = v[j]; v[j] = t;
    }
}

// ---------------------------------------------------------------------------
// Kernel 1: 2 threads per token (par=0 evolves the re-part via cosd table,
// par=1 the im-part via sind table); blockIdx.y = circuit.
// R6 post-mortem: mid-circuit __shfl_xor lowers to ds_bpermute (DS pipe) and
// dominated; this formulation has ZERO cross-lane ops until the final reduce.
// waves_per_eu(1,4): VGPR budget 512/4=128 >= ~80 live -> no spill, 3-4 waves.
// ---------------------------------------------------------------------------
__global__ __attribute__((amdgpu_waves_per_eu(1, 4)))
__launch_bounds__(256) void qsa_sim(
        const float* __restrict__ x,
        const float* __restrict__ cs,
        float* __restrict__ zq,
        float* __restrict__ kv) {
    int g = blockIdx.x * 256 + threadIdx.x;
    int par = g & 1;
    int token = g >> 1;
    int circ = blockIdx.y;
    const float* T = cs + circ * CSTRIDE;
    const float* P = T + 128;                 // RY cos/sin pairs

    float v[DIM];
    const float4* xp4 = (const float4*)(x + (size_t)token * DIM);
#pragma unroll
    for (int k = 0; k < DIM / 4; ++k) {
        float4 q = xp4[k];
        v[4*k+0] = q.x; v[4*k+1] = q.y; v[4*k+2] = q.z; v[4*k+3] = q.w;
    }

    // W psi
    whad<32>(v); whad<16>(v); whad<8>(v); whad<4>(v); whad<2>(v); whad<1>(v);
    // pointwise table (cosd for re-thread, sind for im-thread)
    const float4* tp4 = (const float4*)(T + par * 64);
#pragma unroll
    for (int k = 0; k < DIM / 4; ++k) {
        float4 q = tp4[k];
        v[4*k+0] *= q.x; v[4*k+1] *= q.y; v[4*k+2] *= q.z; v[4*k+3] *= q.w;
    }
    // W again -> state after full RX layer (this thread's re/im part)
    whad<32>(v); whad<16>(v); whad<8>(v); whad<4>(v); whad<2>(v); whad<1>(v);

    // RY0 layer (real rotations), wires 0..5
    ryr<32>(v, P[0],  P[1]);
    ryr<16>(v, P[2],  P[3]);
    ryr< 8>(v, P[4],  P[5]);
    ryr< 4>(v, P[6],  P[7]);
    ryr< 2>(v, P[8],  P[9]);
    ryr< 1>(v, P[10], P[11]);
    // CNOT ring (0,1)(1,2)(2,3)(3,4)(4,5)(5,0) — pure register renames
    cnr<32,16>(v);
    cnr<16, 8>(v);
    cnr< 8, 4>(v);
    cnr< 4, 2>(v);
    cnr< 2, 1>(v);
    cnr< 1,32>(v);
    // RY1 layer
    ryr<32>(v, P[12], P[13]);
    ryr<16>(v, P[14], P[15]);
    ryr< 8>(v, P[16], P[17]);
    ryr< 4>(v, P[18], P[19]);
    ryr< 2>(v, P[20], P[21]);
    ryr< 1>(v, P[22], P[23]);

    // <Z_w> = (2*S_w - norm)/norm; S_w, norm summed over re- and im-threads.
    if (circ < 2) {
        float nl = 0.f, s0 = 0.f;
#pragma unroll
        for (int i = 0; i < DIM; ++i) {
            float p2 = v[i] * v[i];
            nl += p2;
            if (!(i & 32)) s0 += p2;
        }
        float norm2 = nl + __shfl_xor(nl, 1, 64);
        float S0 = s0 + __shfl_xor(s0, 1, 64);
        float z0 = (2.f * S0 - norm2) / norm2;
        if (par == 0) {
            if (circ == 0) zq[token] = SQRT6F * z0;   // a_t, natural-exp scale
            else           kv[(size_t)token * 8] = z0;
        }
    } else {
        float nl = 0.f, s0=0.f, s1=0.f, s2=0.f, s3=0.f, s4=0.f, s5=0.f;
#pragma unroll
        for (int i = 0; i < DIM; ++i) {
            float p2 = v[i] * v[i];
            nl += p2;
            if (!(i & 32)) s0 += p2;
            if (!(i & 16)) s1 += p2;
            if (!(i &  8)) s2 += p2;
            if (!(i &  4)) s3 += p2;
            if (!(i &  2)) s4 += p2;
            if (!(i &  1)) s5 += p2;
        }
        float norm2 = nl + __shfl_xor(nl, 1, 64);
        float S0 = s0 + __shfl_xor(s0, 1, 64);
        float S1 = s1 + __shfl_xor(s1, 1, 64);
        float S2 = s2 + __shfl_xor(s2, 1, 64);
        float S3 = s3 + __shfl_xor(s3, 1, 64);
        float S4 = s4 + __shfl_xor(s4, 1, 64);
        float S5 = s5 + __shfl_xor(s5, 1, 64);
        float inv = 1.0f / norm2;
        float* o = kv + (size_t)token * 8;
        if (par == 0) {
            o[1] = (2.f*S0 - norm2) * inv;
            o[2] = (2.f*S1 - norm2) * inv;
            o[3] = (2.f*S2 - norm2) * inv;
        } else {
            o[4] = (2.f*S3 - norm2) * inv;
            o[5] = (2.f*S4 - norm2) * inv;
            o[6] = (2.f*S5 - norm2) * inv;
        }
    }
}

// ---------------------------------------------------------------------------
// Kernel 2: partial power moments per (batch, chunk-of-256).
// S_m = sum z^m, H_{m,w} = sum z^m * v_w, m=0..15.  112 register accumulators,
// butterfly-reduced across the wave; lane 0 stores 112 floats.
// ---------------------------------------------------------------------------
__global__ __attribute__((amdgpu_waves_per_eu(1, 2)))
__launch_bounds__(64) void qsa_moments_partial(
        const float* __restrict__ kv,
        float* __restrict__ mpart) {
    int blk = blockIdx.x;             // 16 batches * 8 chunks
    int b = blk >> 3, c = blk & 7;
    int lane = threadIdx.x;
    float S[NMOM], H[NMOM][6];
#pragma unroll
    for (int m = 0; m < NMOM; ++m) {
        S[m] = 0.f;
#pragma unroll
        for (int w = 0; w < 6; ++w) H[m][w] = 0.f;
    }
    const float* base = kv + ((size_t)(b * TPB + c * 256)) * 8;
#pragma unroll
    for (int r = 0; r < 4; ++r) {
        const float4* e = (const float4*)(base + (size_t)(r * 64 + lane) * 8);
        float4 e0 = e[0], e1 = e[1];
        float z = e0.x;
        float v0 = e0.y, v1 = e0.z, v2 = e0.w, v3 = e1.x, v4 = e1.y, v5 = e1.z;
        float pw = 1.f;
#pragma unroll
        for (int m = 0; m < NMOM; ++m) {
            S[m] += pw;
            H[m][0] += pw * v0; H[m][1] += pw * v1; H[m][2] += pw * v2;
            H[m][3] += pw * v3; H[m][4] += pw * v4; H[m][5] += pw * v5;
            pw *= z;
        }
    }
#pragma unroll
    for (int d = 32; d >= 1; d >>= 1) {
#pragma unroll
        for (int m = 0; m < NMOM; ++m) {
            S[m] += __shfl_xor(S[m], d, 64);
#pragma unroll
            for (int w = 0; w < 6; ++w) H[m][w] += __shfl_xor(H[m][w], d, 64);
        }
    }
    if (lane == 0) {
        float* o = mpart + (size_t)blk * 112;
#pragma unroll
        for (int m = 0; m < NMOM; ++m) {
            float* om = o + m * 7;
            om[0] = S[m];
            om[1] = H[m][0]; om[2] = H[m][1]; om[3] = H[m][2];
            om[4] = H[m][3]; om[5] = H[m][4]; om[6] = H[m][5];
        }
    }
}

// ---------------------------------------------------------------------------
// Kernel 3: fused combine + per-token evaluation (one block = 256 tokens,
// all in one batch). Stage-1: reduce this batch's 8 chunk-partials into LDS.
// Stage-2: den = sum_m p_m S_m, out_w = sum_m p_m H_mw, p_m = a^m/m!.
// LDS reads in the poly loop are wave-uniform broadcasts (conflict-free).
// ---------------------------------------------------------------------------
__global__ __launch_bounds__(256) void qsa_eval(
        const float* __restrict__ zq,
        const float* __restrict__ mpart,
        float* __restrict__ out) {
    __shared__ float sm[112];
    int bk = blockIdx.x;                      // 128 blocks
    int b = bk >> 3;                          // 8 blocks per batch
    int tid = threadIdx.x;
    if (tid < 112) {
        float s = 0.f;
#pragma unroll
        for (int c = 0; c < 8; ++c) s += mpart[(size_t)(b * 8 + c) * 112 + tid];
        sm[tid] = s;
    }
    __syncthreads();

    int t = bk * 256 + tid;
    float a = zq[t];
    float den = 0.f, o0 = 0.f, o1 = 0.f, o2 = 0.f, o3 = 0.f, o4 = 0.f, o5 = 0.f;
    float pw = 1.f;
#pragma unroll
    for (int m = 0; m < NMOM; ++m) {
        const float* mm = sm + m * 7;
        den += pw * mm[0];
        o0 += pw * mm[1]; o1 += pw * mm[2]; o2 += pw * mm[3];
        o3 += pw * mm[4]; o4 += pw * mm[5]; o5 += pw * mm[6];
        pw *= a * (1.0f / (m + 1));           // p_{m+1} = p_m * a/(m+1)
    }
    float inv = 1.0f / den;
    float* o = out + (size_t)t * 6;
    float2* o2p = (float2*)o;                 // t*24B is 8-aligned
    o2p[0] = make_float2(o0 * inv, o1 * inv);
    o2p[1] = make_float2(o2 * inv, o3 * inv);
    o2p[2] = make_float2(o4 * inv, o5 * inv);
}

// ---------------------------------------------------------------------------
extern "C" void kernel_launch(void* const* d_in, const int* in_sizes, int n_in,
                              void* d_out, int out_size, void* d_ws, size_t ws_size,
                              hipStream_t stream) {
    const float* x  = (const float*)d_in[0];
    const float* pq = (const float*)d_in[1];
    const float* pk = (const float*)d_in[2];
    const float* pv = (const float*)d_in[3];
    float* w = (float*)d_ws;
    // ws (floats): cs[512] | zq[32768] | kv[262144] | mpart[128*112]
    float* cs    = w;
    float* zq    = w + 512;
    float* kv    = w + 512 + NTOK;
    float* mpart = w + 512 + NTOK + NTOK * 8;
    float* out   = (float*)d_out;

    qsa_prep<<<1, 64, 0, stream>>>(pq, pk, pv, cs);
    qsa_sim<<<dim3(NTOK * 2 / 256, 3), 256, 0, stream>>>(x, cs, zq, kv);
    qsa_moments_partial<<<NBATCH * 8, 64, 0, stream>>>(kv, mpart);
    qsa_eval<<<NTOK / 256, 256, 0, stream>>>(zq, mpart, out);
}